// Round 5
// baseline (599.209 us; speedup 1.0000x reference)
//
#include <hip/hip_runtime.h>

#define Tn 200
#define Dn 64
#define Hn 64
#define CC 8    // timesteps per LDS chunk

typedef _Float16 half2v __attribute__((ext_vector_type(2)));
typedef _Float16 half8v __attribute__((ext_vector_type(8)));

__device__ __forceinline__ float fast_sigmoid(float v) {
    return __builtin_amdgcn_rcpf(1.0f + __expf(-v));
}
__device__ __forceinline__ float fast_tanh(float v) {
    return 1.0f - 2.0f * __builtin_amdgcn_rcpf(1.0f + __expf(2.0f * v));
}
// Intra-wave LDS ordering (wave64 lockstep): drain lgkm queue + compiler fence.
__device__ __forceinline__ void wave_lds_fence() {
    asm volatile("s_waitcnt lgkmcnt(0)" ::: "memory");
}

// 2 rows per block: consumer interleaves two independent recurrences so the
// second row's dot2 issue fills the first row's LDS-roundtrip latency.
// Weight regs are SHARED between rows (same column j) -> still 96 half2/wave.
__global__ __launch_bounds__(128, 2)
void augru_fused(const float* __restrict__ x,     // [B,T,D]
                 const int*   __restrict__ slen,  // [B]
                 const float* __restrict__ att,   // [B,T]
                 const float* __restrict__ gk,    // [128][128] cols r|u
                 const float* __restrict__ gb,    // [128]
                 const float* __restrict__ ck,    // [128][64]
                 const float* __restrict__ cb,    // [64]
                 float* __restrict__ out)         // [B,T,H]
{
    const int tid  = threadIdx.x;
    const int wave = tid >> 6;
    const int j    = tid & 63;
    const int b0   = blockIdx.x * 2;
    const int b1   = b0 + 1;

    __shared__ float s_P[2][2][CC][3][Hn];       // [buf][row][t][r|u|c][col], fp32
    __shared__ float s_att[2][2][CC];
    __shared__ __align__(16) _Float16 s_h[2][Hn];
    __shared__ __align__(16) _Float16 s_rh[2][Hn];

    const int len0 = slen[b0];
    const int len1 = slen[b1];
    const int tmax = max(len0, len1);
    const int nch  = (tmax + CC - 1) / CC;

    const float* x0 = x   + (size_t)b0 * Tn * Dn;
    const float* x1 = x   + (size_t)b1 * Tn * Dn;
    const float* a0 = att + (size_t)b0 * Tn;
    const float* a1 = att + (size_t)b1 * Tn;
    float*       o0 = out + (size_t)b0 * Tn * Hn;
    float*       o1 = out + (size_t)b1 * Tn * Hn;

    if (wave == 0) {
        // ========== producer: P[t] = x_t @ W_x + bias, both rows ==========
        half2v wr[32], wu[32], wc[32];   // x-part weight cols (K rows 0..63)
#pragma unroll
        for (int m = 0; m < 32; ++m) {
            const int k = 2 * m;
            wr[m] = half2v{(_Float16)gk[(k + 0) * 128 + j],
                           (_Float16)gk[(k + 1) * 128 + j]};
            wu[m] = half2v{(_Float16)gk[(k + 0) * 128 + 64 + j],
                           (_Float16)gk[(k + 1) * 128 + 64 + j]};
            wc[m] = half2v{(_Float16)ck[(k + 0) * 64 + j],
                           (_Float16)ck[(k + 1) * 64 + j]};
        }
        const float br = gb[j], bu = gb[64 + j], bc = cb[j];

        for (int c = 0; c < nch; ++c) {
            const int t0 = c * CC;
#pragma unroll
            for (int row = 0; row < 2; ++row) {
                const float* xr   = row ? x1 : x0;
                const int    tendr = min(row ? len1 : len0, t0 + CC);
                for (int t = t0; t < tendr; ++t) {
                    const float4* xv = (const float4*)(xr + t * Dn);  // lane-uniform
                    float r0 = br, r1 = 0.f, u0 = bu, u1 = 0.f, c0 = bc, c1 = 0.f;
#pragma unroll
                    for (int kk = 0; kk < 16; ++kk) {
                        const float4 q = xv[kk];
                        const half2v p0 = half2v{(_Float16)q.x, (_Float16)q.y};
                        const half2v p1 = half2v{(_Float16)q.z, (_Float16)q.w};
                        const int m = 2 * kk;
                        r0 = __builtin_amdgcn_fdot2(p0, wr[m],     r0, false);
                        r1 = __builtin_amdgcn_fdot2(p1, wr[m + 1], r1, false);
                        u0 = __builtin_amdgcn_fdot2(p0, wu[m],     u0, false);
                        u1 = __builtin_amdgcn_fdot2(p1, wu[m + 1], u1, false);
                        c0 = __builtin_amdgcn_fdot2(p0, wc[m],     c0, false);
                        c1 = __builtin_amdgcn_fdot2(p1, wc[m + 1], c1, false);
                    }
                    const int lt = t - t0;
                    s_P[c & 1][row][lt][0][j] = r0 + r1;
                    s_P[c & 1][row][lt][1][j] = u0 + u1;
                    s_P[c & 1][row][lt][2][j] = c0 + c1;
                }
            }
            if (j < CC)                      s_att[c & 1][0][j]      = a0[t0 + j];
            else if (j >= 16 && j < 16 + CC) s_att[c & 1][1][j - 16] = a1[t0 + j - 16];
            __syncthreads();  // hand buffer c&1 to consumer
        }
    } else {
        // ========== consumer: two interleaved serial recurrences ==========
        half2v wr[32], wu[32], wc[32];   // h-part weight cols (K rows 64..127)
#pragma unroll
        for (int m = 0; m < 32; ++m) {
            const int k = 64 + 2 * m;
            wr[m] = half2v{(_Float16)gk[(k + 0) * 128 + j],
                           (_Float16)gk[(k + 1) * 128 + j]};
            wu[m] = half2v{(_Float16)gk[(k + 0) * 128 + 64 + j],
                           (_Float16)gk[(k + 1) * 128 + 64 + j]};
            wc[m] = half2v{(_Float16)ck[(k + 0) * 64 + j],
                           (_Float16)ck[(k + 1) * 64 + j]};
        }
        float hA = 0.0f, hB = 0.0f;

        for (int c = 0; c < nch; ++c) {
            __syncthreads();  // wait for producer fill of buffer c&1
            const int t0   = c * CC;
            const int tend = min(tmax, t0 + CC);
            for (int t = t0; t < tend; ++t) {
                const int lt = t - t0;
                // step inputs (independent of h chain)
                const float prA = s_P[c & 1][0][lt][0][j];
                const float puA = s_P[c & 1][0][lt][1][j];
                const float pcA = s_P[c & 1][0][lt][2][j];
                const float prB = s_P[c & 1][1][lt][0][j];
                const float puB = s_P[c & 1][1][lt][1][j];
                const float pcB = s_P[c & 1][1][lt][2][j];
                const float aA  = s_att[c & 1][0][lt];
                const float aB  = s_att[c & 1][1][lt];

                s_h[0][j] = (_Float16)hA;
                s_h[1][j] = (_Float16)hB;
                wave_lds_fence();

                float rA0 = prA, rA1 = 0.f, uA0 = puA, uA1 = 0.f;
                float rB0 = prB, rB1 = 0.f, uB0 = puB, uB1 = 0.f;
                const half8v* hvA = (const half8v*)s_h[0];
                const half8v* hvB = (const half8v*)s_h[1];
#pragma unroll
                for (int m8 = 0; m8 < 8; ++m8) {
                    const half8v vA = hvA[m8];
                    const half8v vB = hvB[m8];
                    const int m = m8 * 4;
                    const half2v a0p = __builtin_shufflevector(vA, vA, 0, 1);
                    const half2v a1p = __builtin_shufflevector(vA, vA, 2, 3);
                    const half2v a2p = __builtin_shufflevector(vA, vA, 4, 5);
                    const half2v a3p = __builtin_shufflevector(vA, vA, 6, 7);
                    const half2v b0p = __builtin_shufflevector(vB, vB, 0, 1);
                    const half2v b1p = __builtin_shufflevector(vB, vB, 2, 3);
                    const half2v b2p = __builtin_shufflevector(vB, vB, 4, 5);
                    const half2v b3p = __builtin_shufflevector(vB, vB, 6, 7);
                    rA0 = __builtin_amdgcn_fdot2(a0p, wr[m + 0], rA0, false);
                    rB0 = __builtin_amdgcn_fdot2(b0p, wr[m + 0], rB0, false);
                    rA1 = __builtin_amdgcn_fdot2(a1p, wr[m + 1], rA1, false);
                    rB1 = __builtin_amdgcn_fdot2(b1p, wr[m + 1], rB1, false);
                    rA0 = __builtin_amdgcn_fdot2(a2p, wr[m + 2], rA0, false);
                    rB0 = __builtin_amdgcn_fdot2(b2p, wr[m + 2], rB0, false);
                    rA1 = __builtin_amdgcn_fdot2(a3p, wr[m + 3], rA1, false);
                    rB1 = __builtin_amdgcn_fdot2(b3p, wr[m + 3], rB1, false);
                    uA0 = __builtin_amdgcn_fdot2(a0p, wu[m + 0], uA0, false);
                    uB0 = __builtin_amdgcn_fdot2(b0p, wu[m + 0], uB0, false);
                    uA1 = __builtin_amdgcn_fdot2(a1p, wu[m + 1], uA1, false);
                    uB1 = __builtin_amdgcn_fdot2(b1p, wu[m + 1], uB1, false);
                    uA0 = __builtin_amdgcn_fdot2(a2p, wu[m + 2], uA0, false);
                    uB0 = __builtin_amdgcn_fdot2(b2p, wu[m + 2], uB0, false);
                    uA1 = __builtin_amdgcn_fdot2(a3p, wu[m + 3], uA1, false);
                    uB1 = __builtin_amdgcn_fdot2(b3p, wu[m + 3], uB1, false);
                }
                const float rgA = fast_sigmoid(rA0 + rA1);
                const float ugA = fast_sigmoid(uA0 + uA1);
                const float rgB = fast_sigmoid(rB0 + rB1);
                const float ugB = fast_sigmoid(uB0 + uB1);

                s_rh[0][j] = (_Float16)(rgA * hA);
                s_rh[1][j] = (_Float16)(rgB * hB);
                wave_lds_fence();

                float cA0 = pcA, cA1 = 0.f, cB0 = pcB, cB1 = 0.f;
                const half8v* rvA = (const half8v*)s_rh[0];
                const half8v* rvB = (const half8v*)s_rh[1];
#pragma unroll
                for (int m8 = 0; m8 < 8; ++m8) {
                    const half8v vA = rvA[m8];
                    const half8v vB = rvB[m8];
                    const int m = m8 * 4;
                    const half2v a0p = __builtin_shufflevector(vA, vA, 0, 1);
                    const half2v a1p = __builtin_shufflevector(vA, vA, 2, 3);
                    const half2v a2p = __builtin_shufflevector(vA, vA, 4, 5);
                    const half2v a3p = __builtin_shufflevector(vA, vA, 6, 7);
                    const half2v b0p = __builtin_shufflevector(vB, vB, 0, 1);
                    const half2v b1p = __builtin_shufflevector(vB, vB, 2, 3);
                    const half2v b2p = __builtin_shufflevector(vB, vB, 4, 5);
                    const half2v b3p = __builtin_shufflevector(vB, vB, 6, 7);
                    cA0 = __builtin_amdgcn_fdot2(a0p, wc[m + 0], cA0, false);
                    cB0 = __builtin_amdgcn_fdot2(b0p, wc[m + 0], cB0, false);
                    cA1 = __builtin_amdgcn_fdot2(a1p, wc[m + 1], cA1, false);
                    cB1 = __builtin_amdgcn_fdot2(b1p, wc[m + 1], cB1, false);
                    cA0 = __builtin_amdgcn_fdot2(a2p, wc[m + 2], cA0, false);
                    cB0 = __builtin_amdgcn_fdot2(b2p, wc[m + 2], cB0, false);
                    cA1 = __builtin_amdgcn_fdot2(a3p, wc[m + 3], cA1, false);
                    cB1 = __builtin_amdgcn_fdot2(b3p, wc[m + 3], cB1, false);
                }
                const float cgA = fast_tanh(cA0 + cA1);
                const float cgB = fast_tanh(cB0 + cB1);

                if (t < len0) {  // wave-uniform branch
                    const float uh = (1.0f - aA) * ugA;
                    hA = uh * hA + (1.0f - uh) * cgA;
                    o0[t * Hn + j] = hA;
                }
                if (t < len1) {
                    const float uh = (1.0f - aB) * ugB;
                    hB = uh * hB + (1.0f - uh) * cgB;
                    o1[t * Hn + j] = hB;
                }
                wave_lds_fence();  // WAR before next t's s_h/s_rh writes
            }
        }
    }

    // ---- zero tails (both waves, disjoint from valid writes) ----
    float4 z;
    z.x = z.y = z.z = z.w = 0.0f;
    {
        float* tail = o0 + len0 * Hn;
        const int total = (Tn - len0) * Hn;
        for (int i = tid * 4; i < total; i += 128 * 4) *(float4*)(tail + i) = z;
    }
    {
        float* tail = o1 + len1 * Hn;
        const int total = (Tn - len1) * Hn;
        for (int i = tid * 4; i < total; i += 128 * 4) *(float4*)(tail + i) = z;
    }
}

extern "C" void kernel_launch(void* const* d_in, const int* in_sizes, int n_in,
                              void* d_out, int out_size, void* d_ws, size_t ws_size,
                              hipStream_t stream) {
    const float* x    = (const float*)d_in[0];
    const int*   slen = (const int*)  d_in[1];
    const float* att  = (const float*)d_in[2];
    const float* gk   = (const float*)d_in[3];
    const float* gb   = (const float*)d_in[4];
    const float* ck   = (const float*)d_in[5];
    const float* cb   = (const float*)d_in[6];
    float* out = (float*)d_out;

    const int B = in_sizes[1];  // 2048
    augru_fused<<<B / 2, 128, 0, stream>>>(x, slen, att, gk, gb, ck, cb, out);
}

// Round 6
// 475.401 us; speedup vs baseline: 1.2604x; 1.2604x over previous
//
#include <hip/hip_runtime.h>

#define Tn 200
#define Dn 64
#define Hn 64
#define CC 16   // chunk size for fallback kernel

typedef _Float16 half2v __attribute__((ext_vector_type(2)));
typedef _Float16 half8v __attribute__((ext_vector_type(8)));

__device__ __forceinline__ float fast_sigmoid(float v) {
    return __builtin_amdgcn_rcpf(1.0f + __expf(-v));
}
__device__ __forceinline__ float fast_tanh(float v) {
    return 1.0f - 2.0f * __builtin_amdgcn_rcpf(1.0f + __expf(2.0f * v));
}
// Intra-wave LDS ordering (wave64 lockstep): drain lgkm queue + compiler fence.
__device__ __forceinline__ void wave_lds_fence() {
    asm volatile("s_waitcnt lgkmcnt(0)" ::: "memory");
}

// ============================================================================
// Kernel 1: time-parallel x-projection. P[b][t][g*64+j] = x_t . Wx[:,g,j] + bias
// Pure throughput: 4 waves/block stride over t, no recurrence, no barriers.
// ============================================================================
__global__ __launch_bounds__(256, 2)
void augru_proj(const float* __restrict__ x,     // [B,T,D]
                const int*   __restrict__ slen,  // [B]
                const float* __restrict__ gk,    // [128][128] cols r|u
                const float* __restrict__ gb,    // [128]
                const float* __restrict__ ck,    // [128][64]
                const float* __restrict__ cb,    // [64]
                _Float16* __restrict__ P)        // [B,T,3,64] fp16
{
    const int b   = blockIdx.x;
    const int tid = threadIdx.x;
    const int w   = tid >> 6;
    const int j   = tid & 63;

    half2v wr[32], wu[32], wc[32];   // x-part weight cols (K rows 0..63)
#pragma unroll
    for (int m = 0; m < 32; ++m) {
        const int k = 2 * m;
        wr[m] = half2v{(_Float16)gk[(k + 0) * 128 + j],
                       (_Float16)gk[(k + 1) * 128 + j]};
        wu[m] = half2v{(_Float16)gk[(k + 0) * 128 + 64 + j],
                       (_Float16)gk[(k + 1) * 128 + 64 + j]};
        wc[m] = half2v{(_Float16)ck[(k + 0) * 64 + j],
                       (_Float16)ck[(k + 1) * 64 + j]};
    }
    const float br = gb[j], bu = gb[64 + j], bc = cb[j];
    const int len = slen[b];

    const float* xrow = x + (size_t)b * Tn * Dn;
    _Float16*    Prow = P + (size_t)b * Tn * 192;

    for (int t = w; t < len; t += 4) {
        const float4* xv = (const float4*)(xrow + t * Dn);  // lane-uniform
        float r0 = br, r1 = 0.f, u0 = bu, u1 = 0.f, c0 = bc, c1 = 0.f;
#pragma unroll
        for (int kk = 0; kk < 16; ++kk) {
            const float4 q = xv[kk];
            const half2v p0 = half2v{(_Float16)q.x, (_Float16)q.y};
            const half2v p1 = half2v{(_Float16)q.z, (_Float16)q.w};
            const int m = 2 * kk;
            r0 = __builtin_amdgcn_fdot2(p0, wr[m],     r0, false);
            r1 = __builtin_amdgcn_fdot2(p1, wr[m + 1], r1, false);
            u0 = __builtin_amdgcn_fdot2(p0, wu[m],     u0, false);
            u1 = __builtin_amdgcn_fdot2(p1, wu[m + 1], u1, false);
            c0 = __builtin_amdgcn_fdot2(p0, wc[m],     c0, false);
            c1 = __builtin_amdgcn_fdot2(p1, wc[m + 1], c1, false);
        }
        _Float16* Pt = Prow + t * 192;
        Pt[j]       = (_Float16)(r0 + r1);   // coalesced 128B per gate group
        Pt[64 + j]  = (_Float16)(u0 + u1);
        Pt[128 + j] = (_Float16)(c0 + c1);
    }
}

// ============================================================================
// Kernel 2: recurrence only. 1 wave per row -> all 2048 rows resident at once,
// no barriers, P/att prefetched 1 step ahead in registers.
// ============================================================================
__global__ __launch_bounds__(64, 2)
void augru_rec(const _Float16* __restrict__ P,   // [B,T,3,64] fp16
               const int*     __restrict__ slen, // [B]
               const float*   __restrict__ att,  // [B,T]
               const float*   __restrict__ gk,   // [128][128]
               const float*   __restrict__ ck,   // [128][64]
               float*         __restrict__ out)  // [B,T,H]
{
    const int b = blockIdx.x;
    const int j = threadIdx.x;

    __shared__ __align__(16) _Float16 s_h[Hn];
    __shared__ __align__(16) _Float16 s_rh[Hn];

    half2v wr[32], wu[32], wc[32];   // h-part weight cols (K rows 64..127)
#pragma unroll
    for (int m = 0; m < 32; ++m) {
        const int k = 64 + 2 * m;
        wr[m] = half2v{(_Float16)gk[(k + 0) * 128 + j],
                       (_Float16)gk[(k + 1) * 128 + j]};
        wu[m] = half2v{(_Float16)gk[(k + 0) * 128 + 64 + j],
                       (_Float16)gk[(k + 1) * 128 + 64 + j]};
        wc[m] = half2v{(_Float16)ck[(k + 0) * 64 + j],
                       (_Float16)ck[(k + 1) * 64 + j]};
    }

    const int len = slen[b];
    const _Float16* Prow = P   + (size_t)b * Tn * 192;
    const float*    arow = att + (size_t)b * Tn;
    float*          orow = out + (size_t)b * Tn * Hn;

    float h = 0.0f;

    // 1-step register prefetch pipeline: raw fp16 regs, convert at consume so
    // the vmcnt wait lands a full step after issue.
    _Float16 pr_n = (_Float16)0, pu_n = (_Float16)0, pc_n = (_Float16)0;
    float a_n = 0.0f;
    if (len > 0) {
        pr_n = Prow[j]; pu_n = Prow[64 + j]; pc_n = Prow[128 + j];
        a_n  = arow[0];
    }

    for (int t = 0; t < len; ++t) {
        const float pr = (float)pr_n;    // loaded last iteration
        const float pu = (float)pu_n;
        const float pc = (float)pc_n;
        const float a  = a_n;
        // issue next step's loads now (unconditional: clamp to last valid row)
        const int tn = min(t + 1, len - 1);
        const _Float16* Pt = Prow + tn * 192;
        pr_n = Pt[j]; pu_n = Pt[64 + j]; pc_n = Pt[128 + j];
        a_n  = arow[tn];

        s_h[j] = (_Float16)h;
        wave_lds_fence();

        float r0 = pr, r1 = 0.f, u0 = pu, u1 = 0.f;
        const half8v* hv = (const half8v*)s_h;   // 8 x 16B broadcast reads
#pragma unroll
        for (int m8 = 0; m8 < 8; ++m8) {
            const half8v v = hv[m8];
            const half2v p0 = __builtin_shufflevector(v, v, 0, 1);
            const half2v p1 = __builtin_shufflevector(v, v, 2, 3);
            const half2v p2 = __builtin_shufflevector(v, v, 4, 5);
            const half2v p3 = __builtin_shufflevector(v, v, 6, 7);
            const int m = m8 * 4;
            r0 = __builtin_amdgcn_fdot2(p0, wr[m + 0], r0, false);
            r1 = __builtin_amdgcn_fdot2(p1, wr[m + 1], r1, false);
            r0 = __builtin_amdgcn_fdot2(p2, wr[m + 2], r0, false);
            r1 = __builtin_amdgcn_fdot2(p3, wr[m + 3], r1, false);
            u0 = __builtin_amdgcn_fdot2(p0, wu[m + 0], u0, false);
            u1 = __builtin_amdgcn_fdot2(p1, wu[m + 1], u1, false);
            u0 = __builtin_amdgcn_fdot2(p2, wu[m + 2], u0, false);
            u1 = __builtin_amdgcn_fdot2(p3, wu[m + 3], u1, false);
        }
        const float rg = fast_sigmoid(r0 + r1);
        const float ug = fast_sigmoid(u0 + u1);

        s_rh[j] = (_Float16)(rg * h);
        wave_lds_fence();

        float c0 = pc, c1 = 0.f;
        const half8v* rv = (const half8v*)s_rh;
#pragma unroll
        for (int m8 = 0; m8 < 8; ++m8) {
            const half8v v = rv[m8];
            const half2v p0 = __builtin_shufflevector(v, v, 0, 1);
            const half2v p1 = __builtin_shufflevector(v, v, 2, 3);
            const half2v p2 = __builtin_shufflevector(v, v, 4, 5);
            const half2v p3 = __builtin_shufflevector(v, v, 6, 7);
            const int m = m8 * 4;
            c0 = __builtin_amdgcn_fdot2(p0, wc[m + 0], c0, false);
            c1 = __builtin_amdgcn_fdot2(p1, wc[m + 1], c1, false);
            c0 = __builtin_amdgcn_fdot2(p2, wc[m + 2], c0, false);
            c1 = __builtin_amdgcn_fdot2(p3, wc[m + 3], c1, false);
        }
        const float cg = fast_tanh(c0 + c1);

        const float uh = (1.0f - a) * ug;
        h = uh * h + (1.0f - uh) * cg;
        orow[t * Hn + j] = h;
        wave_lds_fence();  // WAR before next t's s_h/s_rh writes
    }

    // ---- zero tail: out[b, len:T, :] = 0 ----
    float4 z;
    z.x = z.y = z.z = z.w = 0.0f;
    float* tail = orow + len * Hn;
    const int total = (Tn - len) * Hn;
    for (int i = j * 4; i < total; i += 64 * 4) {
        *(float4*)(tail + i) = z;
    }
}

// ============================================================================
// Fallback (R4 fused, 430 us) if ws is too small for P.
// ============================================================================
__global__ __launch_bounds__(128, 2)
void augru_fused_fb(const float* __restrict__ x, const int* __restrict__ slen,
                    const float* __restrict__ att, const float* __restrict__ gk,
                    const float* __restrict__ gb, const float* __restrict__ ck,
                    const float* __restrict__ cb, float* __restrict__ out)
{
    const int b    = blockIdx.x;
    const int tid  = threadIdx.x;
    const int wave = tid >> 6;
    const int j    = tid & 63;

    __shared__ float s_P[2][CC][3][Hn];
    __shared__ __align__(16) _Float16 s_h[Hn];
    __shared__ __align__(16) _Float16 s_rh[Hn];

    const int len     = slen[b];
    const int nchunks = (len + CC - 1) / CC;
    const float* xrow = x   + (size_t)b * Tn * Dn;
    const float* arow = att + (size_t)b * Tn;
    float*       orow = out + (size_t)b * Tn * Hn;

    if (wave == 0) {
        half2v wr[32], wu[32], wc[32];
#pragma unroll
        for (int m = 0; m < 32; ++m) {
            const int k = 2 * m;
            wr[m] = half2v{(_Float16)gk[(k + 0) * 128 + j], (_Float16)gk[(k + 1) * 128 + j]};
            wu[m] = half2v{(_Float16)gk[(k + 0) * 128 + 64 + j], (_Float16)gk[(k + 1) * 128 + 64 + j]};
            wc[m] = half2v{(_Float16)ck[(k + 0) * 64 + j], (_Float16)ck[(k + 1) * 64 + j]};
        }
        const float br = gb[j], bu = gb[64 + j], bc = cb[j];
        for (int c = 0; c < nchunks; ++c) {
            const int t0 = c * CC, tend = min(len, t0 + CC);
            for (int t = t0; t < tend; ++t) {
                const float4* xv = (const float4*)(xrow + t * Dn);
                float r0 = br, r1 = 0.f, u0 = bu, u1 = 0.f, c0 = bc, c1 = 0.f;
#pragma unroll
                for (int kk = 0; kk < 16; ++kk) {
                    const float4 q = xv[kk];
                    const half2v p0 = half2v{(_Float16)q.x, (_Float16)q.y};
                    const half2v p1 = half2v{(_Float16)q.z, (_Float16)q.w};
                    const int m = 2 * kk;
                    r0 = __builtin_amdgcn_fdot2(p0, wr[m], r0, false);
                    r1 = __builtin_amdgcn_fdot2(p1, wr[m + 1], r1, false);
                    u0 = __builtin_amdgcn_fdot2(p0, wu[m], u0, false);
                    u1 = __builtin_amdgcn_fdot2(p1, wu[m + 1], u1, false);
                    c0 = __builtin_amdgcn_fdot2(p0, wc[m], c0, false);
                    c1 = __builtin_amdgcn_fdot2(p1, wc[m + 1], c1, false);
                }
                const int lt = t - t0;
                s_P[c & 1][lt][0][j] = r0 + r1;
                s_P[c & 1][lt][1][j] = u0 + u1;
                s_P[c & 1][lt][2][j] = c0 + c1;
            }
            __syncthreads();
        }
    } else {
        half2v wr[32], wu[32], wc[32];
#pragma unroll
        for (int m = 0; m < 32; ++m) {
            const int k = 64 + 2 * m;
            wr[m] = half2v{(_Float16)gk[(k + 0) * 128 + j], (_Float16)gk[(k + 1) * 128 + j]};
            wu[m] = half2v{(_Float16)gk[(k + 0) * 128 + 64 + j], (_Float16)gk[(k + 1) * 128 + 64 + j]};
            wc[m] = half2v{(_Float16)ck[(k + 0) * 64 + j], (_Float16)ck[(k + 1) * 64 + j]};
        }
        float h = 0.0f;
        for (int c = 0; c < nchunks; ++c) {
            __syncthreads();
            const int t0 = c * CC, tend = min(len, t0 + CC);
            for (int t = t0; t < tend; ++t) {
                const int lt = t - t0;
                const float pr = s_P[c & 1][lt][0][j];
                const float pu = s_P[c & 1][lt][1][j];
                const float pc = s_P[c & 1][lt][2][j];
                const float a  = arow[t];
                s_h[j] = (_Float16)h;
                wave_lds_fence();
                float r0 = pr, r1 = 0.f, u0 = pu, u1 = 0.f;
                const half8v* hv = (const half8v*)s_h;
#pragma unroll
                for (int m8 = 0; m8 < 8; ++m8) {
                    const half8v v = hv[m8];
                    const half2v p0 = __builtin_shufflevector(v, v, 0, 1);
                    const half2v p1 = __builtin_shufflevector(v, v, 2, 3);
                    const half2v p2 = __builtin_shufflevector(v, v, 4, 5);
                    const half2v p3 = __builtin_shufflevector(v, v, 6, 7);
                    const int m = m8 * 4;
                    r0 = __builtin_amdgcn_fdot2(p0, wr[m + 0], r0, false);
                    r1 = __builtin_amdgcn_fdot2(p1, wr[m + 1], r1, false);
                    r0 = __builtin_amdgcn_fdot2(p2, wr[m + 2], r0, false);
                    r1 = __builtin_amdgcn_fdot2(p3, wr[m + 3], r1, false);
                    u0 = __builtin_amdgcn_fdot2(p0, wu[m + 0], u0, false);
                    u1 = __builtin_amdgcn_fdot2(p1, wu[m + 1], u1, false);
                    u0 = __builtin_amdgcn_fdot2(p2, wu[m + 2], u0, false);
                    u1 = __builtin_amdgcn_fdot2(p3, wu[m + 3], u1, false);
                }
                const float rg = fast_sigmoid(r0 + r1);
                const float ug = fast_sigmoid(u0 + u1);
                s_rh[j] = (_Float16)(rg * h);
                wave_lds_fence();
                float c0 = pc, c1 = 0.f;
                const half8v* rv = (const half8v*)s_rh;
#pragma unroll
                for (int m8 = 0; m8 < 8; ++m8) {
                    const half8v v = rv[m8];
                    const half2v p0 = __builtin_shufflevector(v, v, 0, 1);
                    const half2v p1 = __builtin_shufflevector(v, v, 2, 3);
                    const half2v p2 = __builtin_shufflevector(v, v, 4, 5);
                    const half2v p3 = __builtin_shufflevector(v, v, 6, 7);
                    const int m = m8 * 4;
                    c0 = __builtin_amdgcn_fdot2(p0, wc[m + 0], c0, false);
                    c1 = __builtin_amdgcn_fdot2(p1, wc[m + 1], c1, false);
                    c0 = __builtin_amdgcn_fdot2(p2, wc[m + 2], c0, false);
                    c1 = __builtin_amdgcn_fdot2(p3, wc[m + 3], c1, false);
                }
                const float cg = fast_tanh(c0 + c1);
                const float uh = (1.0f - a) * ug;
                h = uh * h + (1.0f - uh) * cg;
                orow[t * Hn + j] = h;
                wave_lds_fence();
            }
        }
    }
    float4 z; z.x = z.y = z.z = z.w = 0.0f;
    float* tail = orow + len * Hn;
    const int total = (Tn - len) * Hn;
    for (int i = tid * 4; i < total; i += 128 * 4) *(float4*)(tail + i) = z;
}

extern "C" void kernel_launch(void* const* d_in, const int* in_sizes, int n_in,
                              void* d_out, int out_size, void* d_ws, size_t ws_size,
                              hipStream_t stream) {
    const float* x    = (const float*)d_in[0];
    const int*   slen = (const int*)  d_in[1];
    const float* att  = (const float*)d_in[2];
    const float* gk   = (const float*)d_in[3];
    const float* gb   = (const float*)d_in[4];
    const float* ck   = (const float*)d_in[5];
    const float* cb   = (const float*)d_in[6];
    float* out = (float*)d_out;

    const int B = in_sizes[1];  // 2048
    const size_t needP = (size_t)B * Tn * 192 * sizeof(_Float16);  // 157 MB

    if (ws_size >= needP) {
        _Float16* P = (_Float16*)d_ws;
        augru_proj<<<B, 256, 0, stream>>>(x, slen, gk, gb, ck, cb, P);
        augru_rec<<<B, 64, 0, stream>>>(P, slen, att, gk, ck, out);
    } else {
        augru_fused_fb<<<B, 128, 0, stream>>>(x, slen, att, gk, gb, ck, cb, out);
    }
}